// Round 17
// baseline (53.580 us; speedup 1.0000x reference)
//
#include <hip/hip_runtime.h>
#include <math.h>

#define EPS 1e-12f
#define EDIR 0.57735027f
#define M2E  -1.15470054f   // -2*EDIR

#define NB 8      // batches
#define NS 256    // skel points
#define NP 4096   // shape points
#define NM 256    // l3 points

#define NBLK_MEGA 2048

// ws layout (floats) — every slot written every call; no init needed
#define OFF_SKO 0                       // 2048 rows x 4: pmin, norm, ns, nd
#define OFF_C1O (OFF_SKO + 2048*4)      // 2048: per-skel cd1 partial
#define OFF_C2O (OFF_C1O + 2048)        // 4096: per-wave cd2 partial
#define OFF_P2O (OFF_C2O + 4096)        // 4096: per-wave p2s_n partial
#define OFF_SKS (OFF_P2O + 4096)        // 960: skn wave sum
#define OFF_SKQ (OFF_SKS + 960)         // 960: skn wave sumsq

typedef float f4u __attribute__((ext_vector_type(4), aligned(4)));
typedef float f2u __attribute__((ext_vector_type(2), aligned(4)));

__device__ __forceinline__ unsigned umin2(unsigned a, unsigned b){ return a<b?a:b; }
__device__ __forceinline__ unsigned umax2(unsigned a, unsigned b){ return a>b?a:b; }

__device__ __forceinline__ float wave_min(float v){
#pragma unroll
  for (int o = 32; o; o >>= 1) v = fminf(v, __shfl_xor(v, o));
  return v;
}
__device__ __forceinline__ float wave_max(float v){
#pragma unroll
  for (int o = 32; o; o >>= 1) v = fmaxf(v, __shfl_xor(v, o));
  return v;
}
__device__ __forceinline__ float wave_sum(float v){
#pragma unroll
  for (int o = 32; o; o >>= 1) v += __shfl_xor(v, o);
  return v;
}
__device__ __forceinline__ unsigned wave_min_u(unsigned v){
#pragma unroll
  for (int o = 32; o; o >>= 1){ unsigned w = __shfl_xor(v, o); v = (w < v) ? w : v; }
  return v;
}
__device__ __forceinline__ unsigned wave_max_u(unsigned v){
#pragma unroll
  for (int o = 32; o; o >>= 1){ unsigned w = __shfl_xor(v, o); v = (w > v) ? w : v; }
  return v;
}
__device__ __forceinline__ unsigned long long wave_min_u64(unsigned long long v){
#pragma unroll
  for (int o = 32; o; o >>= 1){
    unsigned long long w = __shfl_xor(v, o);
    v = (w < v) ? w : v;
  }
  return v;
}

// cd2 + p2s_n role: 8 shape-rows, 256-skel sweep, analytic corner min
__device__ __forceinline__ void cd2_role(int wv, const float* __restrict__ skel,
                                         const float* __restrict__ rad,
                                         const float* __restrict__ shape,
                                         float* __restrict__ ws, int lane){
  int row0 = wv * 8;                   // 0..32767
  int b    = row0 >> 12;
  float cx[8], cy[8], cz[8];
#pragma unroll
  for (int i = 0; i < 8; ++i){
    f4u qp = *(const f4u*)(shape + (size_t)(row0 + i) * 6);
    cx[i] = qp.x; cy[i] = qp.y; cz[i] = qp.z;
  }
  const float* skb = skel + (size_t)b * NS * 3;
  const float* rdb = rad + (size_t)b * NS;
  float mn[8], pm[8];
#pragma unroll
  for (int i = 0; i < 8; ++i){ mn[i] = 3.4e38f; pm[i] = 3.4e38f; }
#pragma unroll
  for (int it = 0; it < 4; ++it){
    int kidx = it * 64 + lane;
    f2u kxy = *(const f2u*)(skb + (size_t)kidx * 3);
    float kz = skb[(size_t)kidx * 3 + 2];
    float rr = rdb[kidx];
    float r2 = rr * rr;
    float c1 = M2E * rr;
#pragma unroll
    for (int i = 0; i < 8; ++i){
      float dx = cx[i] - kxy.x, dy = cy[i] - kxy.y, dz = cz[i] - kz;
      float q  = fmaf(dx, dx, fmaf(dy, dy, dz * dz));
      float s  = (fabsf(dx) + fabsf(dy)) + fabsf(dz);
      mn[i] = fminf(mn[i], fmaf(c1, s, q + r2));
      float d = sqrtf(fmaxf(q, EPS));
      pm[i] = fminf(pm[i], fabsf(d - rr));
    }
  }
  float cdv = 0.0f, pv = 0.0f;
#pragma unroll
  for (int i = 0; i < 8; ++i){
    float m = wave_min(mn[i]);
    cdv += sqrtf(fmaxf(m, EPS));
    pv  += wave_min(pm[i]);
  }
  if (lane == 0){
    ws[OFF_C2O + wv] = cdv;
    ws[OFF_P2O + wv] = pv;
  }
}

// ---- dispatch 1: mixed-role blocks; fused skelrow+cd1 split over w0/w1 ----
__global__ __launch_bounds__(256) void k_mega(const float* __restrict__ skel,
                                              const float* __restrict__ rad,
                                              const float* __restrict__ nori,
                                              const float* __restrict__ l3,
                                              const float* __restrict__ shape,
                                              float* __restrict__ ws){
  __shared__ float4 lsh[NM];           // skn stage (w3, same-wave RAW)
  __shared__ unsigned wkeys[64 * 13];  // w1 per-lane 12 keys (stride 13: conflict-free)
  __shared__ float wpart[10];          // w1: mn[8], dmo, dmi
  int bid  = blockIdx.x;
  int tid  = threadIdx.x;
  int wid  = tid >> 6;
  int lane = tid & 63;

  if (wid <= 1){
    // ---- fused skelrow+cd1, half sweep per wave (w0: s 0..15, w1: s 16..31) ----
    int row = bid;                    // 0..2047
    int b = row >> 8;
    const float* sjp = skel + (size_t)row * 3;
    float cx = sjp[0], cy = sjp[1], cz = sjp[2];
    float rj = rad[row];
    float r2j = rj * rj;
    float m2re = M2E * rj;
    const float* shb = shape + (size_t)b * NP * 6;
    int s0 = wid * 16;

    unsigned a0=~0u,a1=~0u,a2=~0u,a3=~0u,a4=~0u,a5=~0u;
    unsigned b0=~0u,b1=~0u,b2=~0u,b3=~0u,b4=~0u,b5=~0u;
    float dmoA = 3.4e38f, dmiA = -3.4e38f, dmoB = 3.4e38f, dmiB = -3.4e38f;
    float mn[8];
#pragma unroll
    for (int k = 0; k < 8; ++k) mn[k] = 3.4e38f;

#pragma unroll 2
    for (int si = 0; si < 16; ++si){
      int s = s0 + si;
      int nA = s * 128 + lane;
      int nB = nA + 64;
      f4u qA = *(const f4u*)(shb + (size_t)nA * 6);   // x,y,z,nx
      f4u qB = *(const f4u*)(shb + (size_t)nB * 6);
      float dxA = qA.x - cx, dyA = qA.y - cy, dzA = qA.z - cz;
      float dxB = qB.x - cx, dyB = qB.y - cy, dzB = qB.z - cz;
      float dA = fmaf(dxA, dxA, fmaf(dyA, dyA, dzA * dzA));
      float dB = fmaf(dxB, dxB, fmaf(dyB, dyB, dzB * dzB));
      {
        float s1p = dxA + dyA, s2p = dxA - dyA;
        float ga = s1p + dzA, gb = s1p - dzA, gc = s2p + dzA, gd = s2p - dzA;
        mn[0] = fminf(mn[0], fmaf(m2re,  ga, dA));
        mn[1] = fminf(mn[1], fmaf(m2re,  gb, dA));
        mn[2] = fminf(mn[2], fmaf(m2re,  gc, dA));
        mn[3] = fminf(mn[3], fmaf(m2re,  gd, dA));
        mn[4] = fminf(mn[4], fmaf(m2re, -gd, dA));
        mn[5] = fminf(mn[5], fmaf(m2re, -gc, dA));
        mn[6] = fminf(mn[6], fmaf(m2re, -gb, dA));
        mn[7] = fminf(mn[7], fmaf(m2re, -ga, dA));
      }
      {
        float s1p = dxB + dyB, s2p = dxB - dyB;
        float ga = s1p + dzB, gb = s1p - dzB, gc = s2p + dzB, gd = s2p - dzB;
        mn[0] = fminf(mn[0], fmaf(m2re,  ga, dB));
        mn[1] = fminf(mn[1], fmaf(m2re,  gb, dB));
        mn[2] = fminf(mn[2], fmaf(m2re,  gc, dB));
        mn[3] = fminf(mn[3], fmaf(m2re,  gd, dB));
        mn[4] = fminf(mn[4], fmaf(m2re, -gd, dB));
        mn[5] = fminf(mn[5], fmaf(m2re, -gc, dB));
        mn[6] = fminf(mn[6], fmaf(m2re, -gb, dB));
        mn[7] = fminf(mn[7], fmaf(m2re, -ga, dB));
      }
      bool inA = dA < r2j;
      bool inB = dB < r2j;
      dmoA = fminf(dmoA, inA ? 3.4e38f : dA);
      dmiA = fmaxf(dmiA, inA ? dA : -3.4e38f);
      dmoB = fminf(dmoB, inB ? 3.4e38f : dB);
      dmiB = fmaxf(dmiB, inB ? dB : -3.4e38f);
      unsigned uA = (__float_as_uint(dA) & 0xFFFFF000u) | (unsigned)nA;
      unsigned uB = (__float_as_uint(dB) & 0xFFFFF000u) | (unsigned)nB;
      a5 = umin2(a5, uA);
      { unsigned p = umin2(a4, a5), q = umax2(a4, a5); a4 = p; a5 = q; }
      { unsigned p = umin2(a3, a4), q = umax2(a3, a4); a3 = p; a4 = q; }
      { unsigned p = umin2(a2, a3), q = umax2(a2, a3); a2 = p; a3 = q; }
      { unsigned p = umin2(a1, a2), q = umax2(a1, a2); a1 = p; a2 = q; }
      { unsigned p = umin2(a0, a1), q = umax2(a0, a1); a0 = p; a1 = q; }
      b5 = umin2(b5, uB);
      { unsigned p = umin2(b4, b5), q = umax2(b4, b5); b4 = p; b5 = q; }
      { unsigned p = umin2(b3, b4), q = umax2(b3, b4); b3 = p; b4 = q; }
      { unsigned p = umin2(b2, b3), q = umax2(b2, b3); b2 = p; b3 = q; }
      { unsigned p = umin2(b1, b2), q = umax2(b1, b2); b1 = p; b2 = q; }
      { unsigned p = umin2(b0, b1), q = umax2(b0, b1); b0 = p; b1 = q; }
    }
    // wave-level reductions of this half
    float mnr[8];
#pragma unroll
    for (int k = 0; k < 8; ++k) mnr[k] = wave_min(mn[k]);
    float dmo = wave_min(fminf(dmoA, dmoB));
    float dmi = wave_max(fmaxf(dmiA, dmiB));

    if (wid == 1){
      unsigned* wk = wkeys + lane * 13;
      wk[0]=a0; wk[1]=a1; wk[2]=a2; wk[3]=a3; wk[4]=a4; wk[5]=a5;
      wk[6]=b0; wk[7]=b1; wk[8]=b2; wk[9]=b3; wk[10]=b4; wk[11]=b5;
      if (lane == 0){
#pragma unroll
        for (int k = 0; k < 8; ++k) wpart[k] = mnr[k];
        wpart[8] = dmo; wpart[9] = dmi;
      }
      __syncthreads();
      return;
    }
    // ---- w0: merge ----
    __syncthreads();
    unsigned c0,c1,c2,c3,c4,c5,c6,c7,c8,c9,c10,c11;
    {
      const unsigned* wk = wkeys + lane * 13;
      c0=wk[0]; c1=wk[1]; c2=wk[2]; c3=wk[3]; c4=wk[4]; c5=wk[5];
      c6=wk[6]; c7=wk[7]; c8=wk[8]; c9=wk[9]; c10=wk[10]; c11=wk[11];
    }
    // cd1 output (merged)
    {
      float v = 0.0f;
#pragma unroll
      for (int k = 0; k < 8; ++k){
        float m = fminf(mnr[k], wpart[k]);
        v += sqrtf(fmaxf(m + r2j, EPS));
      }
      if (lane == 0) ws[OFF_C1O + row] = v;
    }
    float dmin_out = fminf(dmo, wpart[8]);
    float dmax_in  = fmaxf(dmi, wpart[9]);
    float pmin = sqrtf(fmaxf(dmin_out, EPS)) - rj;
    float pin  = (dmax_in >= 0.0f) ? (rj - sqrtf(fmaxf(dmax_in, EPS))) : 3.4e38f;
    pmin = fminf(pmin, pin);

    // rank-30 over 24 chains (4 heads: a0, b0, c0, c6)
    unsigned lmin = umin2(umin2(a0, b0), umin2(c0, c6));
    unsigned lo = wave_min_u(lmin), hi = wave_max_u(lmin);
    while (lo < hi){
      unsigned mid = lo + ((hi - lo) >> 1);
      int c = __popcll(__ballot(a0 <= mid)) + __popcll(__ballot(a1 <= mid)) +
              __popcll(__ballot(a2 <= mid)) + __popcll(__ballot(a3 <= mid)) +
              __popcll(__ballot(a4 <= mid)) + __popcll(__ballot(a5 <= mid)) +
              __popcll(__ballot(b0 <= mid)) + __popcll(__ballot(b1 <= mid)) +
              __popcll(__ballot(b2 <= mid)) + __popcll(__ballot(b3 <= mid)) +
              __popcll(__ballot(b4 <= mid)) + __popcll(__ballot(b5 <= mid)) +
              __popcll(__ballot(c0 <= mid)) + __popcll(__ballot(c1 <= mid)) +
              __popcll(__ballot(c2 <= mid)) + __popcll(__ballot(c3 <= mid)) +
              __popcll(__ballot(c4 <= mid)) + __popcll(__ballot(c5 <= mid)) +
              __popcll(__ballot(c6 <= mid)) + __popcll(__ballot(c7 <= mid)) +
              __popcll(__ballot(c8 <= mid)) + __popcll(__ballot(c9 <= mid)) +
              __popcll(__ballot(c10 <= mid)) + __popcll(__ballot(c11 <= mid));
      if (c >= 30) hi = mid; else lo = mid + 1;
    }
    unsigned tau = hi;

    const float* njp = nori + (size_t)row * 3;
    float nx = njp[0], ny = njp[1], nz = njp[2];
    float dsum = 0.0f;
    {
      unsigned mm[24] = {a0,a1,a2,a3,a4,a5,b0,b1,b2,b3,b4,b5,
                         c0,c1,c2,c3,c4,c5,c6,c7,c8,c9,c10,c11};
#pragma unroll
      for (int r = 0; r < 24; ++r){
        if (mm[r] <= tau){
          int idx = (int)(mm[r] & 0xFFFu);
          f4u qq = *(const f4u*)(shb + (size_t)idx * 6 + 2);   // z,nx,ny,nz
          dsum += fabsf(fmaf(nx, qq.y, fmaf(ny, qq.z, nz * qq.w)));
        }
      }
    }
    dsum = wave_sum(dsum);

    // ns: 3 nearest skel points (incl. self)
    const float* skb = skel + (size_t)b * NS * 3;
    const float* nb  = nori + (size_t)b * NS * 3;
    unsigned u0=~0u,u1=~0u,u2=~0u; int i0=0,i1=0,i2=0;
#pragma unroll
    for (int it = 0; it < 4; ++it){
      int n2i = it * 64 + lane;
      f2u kxy = *(const f2u*)(skb + (size_t)n2i * 3);
      float kz = skb[(size_t)n2i * 3 + 2];
      float dx = kxy.x - cx, dy = kxy.y - cy, dz = kz - cz;
      unsigned u = __float_as_uint(fmaf(dx,dx,fmaf(dy,dy,dz*dz)));
      if (u < u2){ u2 = u; i2 = n2i; }
      if (u2 < u1){ unsigned t=u1;u1=u2;u2=t; int ti=i1;i1=i2;i2=ti; }
      if (u1 < u0){ unsigned t=u0;u0=u1;u1=t; int ti=i0;i0=i1;i1=ti; }
    }
    int cc = 0;
    float nssum = 0.0f;
#pragma unroll
    for (int r = 0; r < 3; ++r){
      unsigned hu = (cc==0)?u0:((cc==1)?u1:u2);
      int      hix= (cc==0)?i0:((cc==1)?i1:i2);
      unsigned long long pack = (((unsigned long long)hu) << 32) | (unsigned)hix;
      unsigned long long best = wave_min_u64(pack);
      if (pack == best) cc++;
      int idx = (int)(best & 0xffffffffull);
      if (lane == 0){
        float axn = nb[idx*3+0]-nx, ayn = nb[idx*3+1]-ny, azn = nb[idx*3+2]-nz;
        nssum += sqrtf(fmaf(axn,axn,fmaf(ayn,ayn,azn*azn)) + EPS);
      }
    }

    if (lane == 0){
      float nrm = sqrtf(nx*nx + ny*ny + nz*nz + EPS);
      float ndv = expf(0.3f - nrm) + ((nrm < 0.25f) ? 5.0f : 0.0f);
      float* sko = ws + OFF_SKO + (size_t)row * 4;
      sko[0] = pmin;
      sko[1] = dsum * (1.0f / 30.0f);
      sko[2] = nssum;
      sko[3] = ndv;
    }
    return;
  }

  if (wid == 2){
    cd2_role(bid, skel, rad, shape, ws, lane);
    __syncthreads();
    return;
  }

  // ---- wid == 3: cd2 (second set) + skn (bid < 960) ----
  cd2_role(2048 + bid, skel, rad, shape, ws, lane);
  if (bid < 960){
    int q = bid;
    int b = q / 120;
    int w = q % 120;
    int t = w * 64 + lane;           // 0..7679
    for (int i = lane; i < NM; i += 64){
      const float* lp = l3 + (size_t)(b * NM + i) * 3;
      float lx = lp[0], ly = lp[1], lz = lp[2];
      lsh[i] = make_float4(lx, ly, lz, fmaf(lx, lx, fmaf(ly, ly, lz * lz)));
    }
    int s = t >> 8;
    int j = t & 255;
    float ksf = (float)s * (1.0f / 30.0f);
    const float* sj = skel + (size_t)(b * NS + j) * 3;
    const float* nj = nori + (size_t)(b * NS + j) * 3;
    float px = fmaf(nj[0], ksf, sj[0]);
    float py = fmaf(nj[1], ksf, sj[1]);
    float pz = fmaf(nj[2], ksf, sj[2]);
    float ax = -2.0f * px, ay = -2.0f * py, az = -2.0f * pz;
    float pw = fmaf(px, px, fmaf(py, py, pz * pz));
    float mnv = 3.4e38f;
#pragma unroll 8
    for (int qq = 0; qq < NM; ++qq){
      float4 L = lsh[qq];
      float t2 = fmaf(L.x, ax, fmaf(L.y, ay, fmaf(L.z, az, L.w)));
      mnv = fminf(mnv, t2);
    }
    float d = sqrtf(fmaxf(mnv + pw, EPS));
    float s1 = wave_sum(d);
    float s2 = wave_sum(d * d);
    if (lane == 0){
      ws[OFF_SKS + q] = s1;
      ws[OFF_SKQ + q] = s2;
    }
  }
  __syncthreads();
}

// ---- dispatch 2: finalize (1024 threads) ----
__global__ __launch_bounds__(1024) void k_final(const float* __restrict__ rad,
                                                const float* __restrict__ ws,
                                                const int* w0, const int* w1, const int* w2,
                                                const int* w4, const int* w5, const int* w6,
                                                float* __restrict__ out){
  __shared__ float red[8][16];
  __shared__ float sb1[960], sb2[960];
  __shared__ float bb1[8], bb2[8];
  int tid = threadIdx.x;
  int wid = tid >> 6, lane = tid & 63;

  float pp2sj = 0.0f, pnorm = 0.0f, pns = 0.0f, pnd = 0.0f;
  for (int q = tid; q < 2048; q += 1024){
    float4 s4 = *(const float4*)(ws + OFF_SKO + (size_t)q * 4);
    pp2sj += s4.x; pnorm += s4.y; pns += s4.z; pnd += s4.w;
  }
  float pc1 = 0.0f;
  for (int q = tid; q < 2048; q += 1024) pc1 += ws[OFF_C1O + q];
  float pc2 = 0.0f, pp2n = 0.0f;
  for (int q = tid; q < 4096; q += 1024){
    pc2  += ws[OFF_C2O + q];
    pp2n += ws[OFF_P2O + q];
  }
  float prad = 0.0f;
  for (int q = tid; q < NB * NS; q += 1024) prad += rad[q];

  if (tid < 960){ sb1[tid] = ws[OFF_SKS + tid]; sb2[tid] = ws[OFF_SKQ + tid]; }

  pp2sj = wave_sum(pp2sj); pnorm = wave_sum(pnorm);
  pns = wave_sum(pns);     pnd = wave_sum(pnd);
  pc1 = wave_sum(pc1);     pc2 = wave_sum(pc2);
  pp2n = wave_sum(pp2n);   prad = wave_sum(prad);
  if (lane == 0){
    red[0][wid] = pp2sj; red[1][wid] = pnorm; red[2][wid] = pns; red[3][wid] = pnd;
    red[4][wid] = pc1;   red[5][wid] = pc2;   red[6][wid] = pp2n; red[7][wid] = prad;
  }
  __syncthreads();
  if (tid < 8){
    float s1 = 0.0f, s2 = 0.0f;
    for (int i = 0; i < 120; ++i){ s1 += sb1[tid * 120 + i]; s2 += sb2[tid * 120 + i]; }
    bb1[tid] = s1; bb2[tid] = s2;
  }
  __syncthreads();
  if (tid == 0){
    float acc[8];
#pragma unroll
    for (int r = 0; r < 8; ++r){
      float v = 0.0f;
#pragma unroll
      for (int i = 0; i < 16; ++i) v += red[r][i];
      acc[r] = v;
    }
    float p2sj = acc[0], nrmt = acc[1], nst = acc[2], ndt = acc[3];
    float c1t = acc[4], c2t = acc[5], p2nt = acc[6], srad = acc[7];
    float ls = c1t * (1.0f/2048.0f) + c2t * (1.0f/4096.0f);
    float lp = p2nt * (1.0f/4096.0f) + p2sj * (1.0f/256.0f);
    float lr = -srad * (1.0f/256.0f);
    float ln = nrmt * (1.0f/8.0f);
    float smind = 0.0f, vsum = 0.0f;
    for (int b = 0; b < NB; ++b){
      float s1 = bb1[b], s2 = bb2[b];
      smind += s1;
      vsum  += (s2 - s1 * s1 * (1.0f/7680.0f)) * (1.0f/7679.0f);
    }
    float lskn = 50.0f * smind * (1.0f/(8.0f*7680.0f)) + 500.0f * vsum * (1.0f/8.0f);
    float lnd = ndt * (1.0f/2048.0f);
    float lns = nst * (1.0f/6144.0f);
    float o = (float)w0[0]*ls + (float)w1[0]*lp + (float)w2[0]*lr +
              (float)w4[0]*ln + (float)w5[0]*lskn + (float)w6[0]*lnd + 0.1f*lns;
    out[0] = o;
  }
}

extern "C" void kernel_launch(void* const* d_in, const int* in_sizes, int n_in,
                              void* d_out, int out_size, void* d_ws, size_t ws_size,
                              hipStream_t stream) {
  const float* skel  = (const float*)d_in[0];
  const float* rad   = (const float*)d_in[1];
  const float* nori  = (const float*)d_in[3];
  const float* l3    = (const float*)d_in[5];
  const float* shape = (const float*)d_in[7];
  const int* w0 = (const int*)d_in[9];
  const int* w1 = (const int*)d_in[10];
  const int* w2 = (const int*)d_in[11];
  const int* w4 = (const int*)d_in[13];
  const int* w5 = (const int*)d_in[14];
  const int* w6 = (const int*)d_in[15];
  float* ws  = (float*)d_ws;
  float* out = (float*)d_out;

  k_mega<<<dim3(NBLK_MEGA), dim3(256), 0, stream>>>(skel, rad, nori, l3, shape, ws);
  k_final<<<dim3(1), dim3(1024), 0, stream>>>(rad, ws, w0, w1, w2, w4, w5, w6, out);
}

// Round 18
// 51.109 us; speedup vs baseline: 1.0484x; 1.0484x over previous
//
#include <hip/hip_runtime.h>
#include <math.h>

#define EPS 1e-12f
#define EDIR 0.57735027f
#define M2E  -1.15470054f   // -2*EDIR

#define NB 8      // batches
#define NS 256    // skel points
#define NP 4096   // shape points
#define NM 256    // l3 points

// k_mega: 2048 mixed-role blocks (256 thr): w0=skelrow+cd1 fused, w1/w2=cd2, w3=skn(<960)
#define NBLK_MEGA 2048

// ws layout (floats) — every slot written every call; no init needed
#define OFF_SKO 0                       // 2048 rows x 4: pmin, norm, ns, nd
#define OFF_C1O (OFF_SKO + 2048*4)      // 2048: per-skel cd1 partial
#define OFF_C2O (OFF_C1O + 2048)        // 4096: per-wave cd2 partial
#define OFF_P2O (OFF_C2O + 4096)        // 4096: per-wave p2s_n partial
#define OFF_SKS (OFF_P2O + 4096)        // 960: skn wave sum
#define OFF_SKQ (OFF_SKS + 960)         // 960: skn wave sumsq

// 4-byte-aligned vector loads (hardware dwordx4/dwordx2 need only dword alignment)
typedef float f4u __attribute__((ext_vector_type(4), aligned(4)));
typedef float f2u __attribute__((ext_vector_type(2), aligned(4)));

__device__ __forceinline__ unsigned umin2(unsigned a, unsigned b){ return a<b?a:b; }
__device__ __forceinline__ unsigned umax2(unsigned a, unsigned b){ return a>b?a:b; }

__device__ __forceinline__ float wave_min(float v){
#pragma unroll
  for (int o = 32; o; o >>= 1) v = fminf(v, __shfl_xor(v, o));
  return v;
}
__device__ __forceinline__ float wave_max(float v){
#pragma unroll
  for (int o = 32; o; o >>= 1) v = fmaxf(v, __shfl_xor(v, o));
  return v;
}
__device__ __forceinline__ float wave_sum(float v){
#pragma unroll
  for (int o = 32; o; o >>= 1) v += __shfl_xor(v, o);
  return v;
}
__device__ __forceinline__ unsigned wave_min_u(unsigned v){
#pragma unroll
  for (int o = 32; o; o >>= 1){ unsigned w = __shfl_xor(v, o); v = (w < v) ? w : v; }
  return v;
}
__device__ __forceinline__ unsigned wave_max_u(unsigned v){
#pragma unroll
  for (int o = 32; o; o >>= 1){ unsigned w = __shfl_xor(v, o); v = (w > v) ? w : v; }
  return v;
}
__device__ __forceinline__ unsigned long long wave_min_u64(unsigned long long v){
#pragma unroll
  for (int o = 32; o; o >>= 1){
    unsigned long long w = __shfl_xor(v, o);
    v = (w < v) ? w : v;
  }
  return v;
}

// ---- dispatch 1: mixed-role blocks, raw inputs, indexed outputs, no barriers ----
__global__ __launch_bounds__(256) void k_mega(const float* __restrict__ skel,
                                              const float* __restrict__ rad,
                                              const float* __restrict__ nori,
                                              const float* __restrict__ l3,
                                              const float* __restrict__ shape,
                                              float* __restrict__ ws){
  __shared__ float4 lsh[NM];          // used only by wave 3 (skn), single-wave RAW
  int bid  = blockIdx.x;
  int tid  = threadIdx.x;
  int wid  = tid >> 6;
  int lane = tid & 63;

  if (wid == 0){
    // ---- fused skelrow + cd1: one sweep of shape serves both ----
    int row = bid;                    // 0..2047
    int b = row >> 8;
    const float* sjp = skel + (size_t)row * 3;
    float cx = sjp[0], cy = sjp[1], cz = sjp[2];
    float rj = rad[row];
    float r2j = rj * rj;
    float m2re = M2E * rj;
    const float* njp = nori + (size_t)row * 3;
    float nx = njp[0], ny = njp[1], nz = njp[2];
    const float* shb = shape + (size_t)b * NP * 6;

    unsigned a0=~0u,a1=~0u,a2=~0u,a3=~0u,a4=~0u,a5=~0u;
    unsigned b0=~0u,b1=~0u,b2=~0u,b3=~0u,b4=~0u,b5=~0u;
    float dmoA = 3.4e38f, dmiA = -3.4e38f, dmoB = 3.4e38f, dmiB = -3.4e38f;
    float mn[8];
#pragma unroll
    for (int k = 0; k < 8; ++k) mn[k] = 3.4e38f;

#pragma unroll 2
    for (int s = 0; s < 32; ++s){
      int nA = s * 128 + lane;
      int nB = nA + 64;
      f4u qA = *(const f4u*)(shb + (size_t)nA * 6);   // x,y,z,nx in one dwordx4
      f4u qB = *(const f4u*)(shb + (size_t)nB * 6);
      float dxA = qA.x - cx, dyA = qA.y - cy, dzA = qA.z - cz;
      float dxB = qB.x - cx, dyB = qB.y - cy, dzB = qB.z - cz;
      float dA = fmaf(dxA, dxA, fmaf(dyA, dyA, dzA * dzA));
      float dB = fmaf(dxB, dxB, fmaf(dyB, dyB, dzB * dzB));
      // cd1 corner-folded mins (shared loads)
      {
        float s1p = dxA + dyA, s2p = dxA - dyA;
        float ga = s1p + dzA, gb = s1p - dzA, gc = s2p + dzA, gd = s2p - dzA;
        mn[0] = fminf(mn[0], fmaf(m2re,  ga, dA));
        mn[1] = fminf(mn[1], fmaf(m2re,  gb, dA));
        mn[2] = fminf(mn[2], fmaf(m2re,  gc, dA));
        mn[3] = fminf(mn[3], fmaf(m2re,  gd, dA));
        mn[4] = fminf(mn[4], fmaf(m2re, -gd, dA));
        mn[5] = fminf(mn[5], fmaf(m2re, -gc, dA));
        mn[6] = fminf(mn[6], fmaf(m2re, -gb, dA));
        mn[7] = fminf(mn[7], fmaf(m2re, -ga, dA));
      }
      {
        float s1p = dxB + dyB, s2p = dxB - dyB;
        float ga = s1p + dzB, gb = s1p - dzB, gc = s2p + dzB, gd = s2p - dzB;
        mn[0] = fminf(mn[0], fmaf(m2re,  ga, dB));
        mn[1] = fminf(mn[1], fmaf(m2re,  gb, dB));
        mn[2] = fminf(mn[2], fmaf(m2re,  gc, dB));
        mn[3] = fminf(mn[3], fmaf(m2re,  gd, dB));
        mn[4] = fminf(mn[4], fmaf(m2re, -gd, dB));
        mn[5] = fminf(mn[5], fmaf(m2re, -gc, dB));
        mn[6] = fminf(mn[6], fmaf(m2re, -gb, dB));
        mn[7] = fminf(mn[7], fmaf(m2re, -ga, dB));
      }
      // skelrow tracks
      bool inA = dA < r2j;
      bool inB = dB < r2j;
      dmoA = fminf(dmoA, inA ? 3.4e38f : dA);
      dmiA = fmaxf(dmiA, inA ? dA : -3.4e38f);
      dmoB = fminf(dmoB, inB ? 3.4e38f : dB);
      dmiB = fmaxf(dmiB, inB ? dB : -3.4e38f);
      unsigned uA = (__float_as_uint(dA) & 0xFFFFF000u) | (unsigned)nA;
      unsigned uB = (__float_as_uint(dB) & 0xFFFFF000u) | (unsigned)nB;
      a5 = umin2(a5, uA);
      { unsigned p = umin2(a4, a5), q = umax2(a4, a5); a4 = p; a5 = q; }
      { unsigned p = umin2(a3, a4), q = umax2(a3, a4); a3 = p; a4 = q; }
      { unsigned p = umin2(a2, a3), q = umax2(a2, a3); a2 = p; a3 = q; }
      { unsigned p = umin2(a1, a2), q = umax2(a1, a2); a1 = p; a2 = q; }
      { unsigned p = umin2(a0, a1), q = umax2(a0, a1); a0 = p; a1 = q; }
      b5 = umin2(b5, uB);
      { unsigned p = umin2(b4, b5), q = umax2(b4, b5); b4 = p; b5 = q; }
      { unsigned p = umin2(b3, b4), q = umax2(b3, b4); b3 = p; b4 = q; }
      { unsigned p = umin2(b2, b3), q = umax2(b2, b3); b2 = p; b3 = q; }
      { unsigned p = umin2(b1, b2), q = umax2(b1, b2); b1 = p; b2 = q; }
      { unsigned p = umin2(b0, b1), q = umax2(b0, b1); b0 = p; b1 = q; }
    }
    // cd1 output
    {
      float v = 0.0f;
#pragma unroll
      for (int k = 0; k < 8; ++k){
        float m = wave_min(mn[k]);
        v += sqrtf(fmaxf(m + r2j, EPS));
      }
      if (lane == 0) ws[OFF_C1O + row] = v;
    }
    // skelrow outputs
    float dmin_out = wave_min(fminf(dmoA, dmoB));
    float dmax_in  = wave_max(fmaxf(dmiA, dmiB));
    float pmin = sqrtf(fmaxf(dmin_out, EPS)) - rj;
    float pin  = (dmax_in >= 0.0f) ? (rj - sqrtf(fmaxf(dmax_in, EPS))) : 3.4e38f;
    pmin = fminf(pmin, pin);

    unsigned lmin = umin2(a0, b0);
    unsigned lo = wave_min_u(lmin), hi = wave_max_u(lmin);
    while (lo < hi){
      unsigned mid = lo + ((hi - lo) >> 1);
      int c = __popcll(__ballot(a0 <= mid)) + __popcll(__ballot(a1 <= mid)) +
              __popcll(__ballot(a2 <= mid)) + __popcll(__ballot(a3 <= mid)) +
              __popcll(__ballot(a4 <= mid)) + __popcll(__ballot(a5 <= mid)) +
              __popcll(__ballot(b0 <= mid)) + __popcll(__ballot(b1 <= mid)) +
              __popcll(__ballot(b2 <= mid)) + __popcll(__ballot(b3 <= mid)) +
              __popcll(__ballot(b4 <= mid)) + __popcll(__ballot(b5 <= mid));
      if (c >= 30) hi = mid; else lo = mid + 1;
    }
    unsigned tau = hi;

    float dsum = 0.0f;
    {
      unsigned mm[12] = {a0,a1,a2,a3,a4,a5,b0,b1,b2,b3,b4,b5};
#pragma unroll
      for (int r = 0; r < 12; ++r){
        if (mm[r] <= tau){
          int idx = (int)(mm[r] & 0xFFFu);
          f4u qq = *(const f4u*)(shb + (size_t)idx * 6 + 2);   // z,nx,ny,nz
          dsum += fabsf(fmaf(nx, qq.y, fmaf(ny, qq.z, nz * qq.w)));
        }
      }
    }
    dsum = wave_sum(dsum);

    const float* skb = skel + (size_t)b * NS * 3;
    const float* nb  = nori + (size_t)b * NS * 3;
    unsigned u0=~0u,u1=~0u,u2=~0u; int i0=0,i1=0,i2=0;
#pragma unroll
    for (int it = 0; it < 4; ++it){
      int n2i = it * 64 + lane;
      f2u kxy = *(const f2u*)(skb + (size_t)n2i * 3);
      float kz = skb[(size_t)n2i * 3 + 2];
      float dx = kxy.x - cx, dy = kxy.y - cy, dz = kz - cz;
      unsigned u = __float_as_uint(fmaf(dx,dx,fmaf(dy,dy,dz*dz)));
      if (u < u2){ u2 = u; i2 = n2i; }
      if (u2 < u1){ unsigned t=u1;u1=u2;u2=t; int ti=i1;i1=i2;i2=ti; }
      if (u1 < u0){ unsigned t=u0;u0=u1;u1=t; int ti=i0;i0=i1;i1=ti; }
    }
    int cc = 0;
    float nssum = 0.0f;
#pragma unroll
    for (int r = 0; r < 3; ++r){
      unsigned hu = (cc==0)?u0:((cc==1)?u1:u2);
      int      hix= (cc==0)?i0:((cc==1)?i1:i2);
      unsigned long long pack = (((unsigned long long)hu) << 32) | (unsigned)hix;
      unsigned long long best = wave_min_u64(pack);
      if (pack == best) cc++;
      int idx = (int)(best & 0xffffffffull);
      if (lane == 0){
        float axn = nb[idx*3+0]-nx, ayn = nb[idx*3+1]-ny, azn = nb[idx*3+2]-nz;
        nssum += sqrtf(fmaf(axn,axn,fmaf(ayn,ayn,azn*azn)) + EPS);
      }
    }

    if (lane == 0){
      float nrm = sqrtf(nx*nx + ny*ny + nz*nz + EPS);
      float ndv = expf(0.3f - nrm) + ((nrm < 0.25f) ? 5.0f : 0.0f);
      float* sko = ws + OFF_SKO + (size_t)row * 4;
      sko[0] = pmin;
      sko[1] = dsum * (1.0f / 30.0f);
      sko[2] = nssum;
      sko[3] = ndv;
    }

  } else if (wid <= 2){
    // ---- cd2 + p2s_n: 8 shape-rows per wave; analytic corner min ----
    int wv   = bid * 2 + (wid - 1);      // 0..4095
    int row0 = wv * 8;                   // 0..32767
    int b    = row0 >> 12;
    float cx[8], cy[8], cz[8];
#pragma unroll
    for (int i = 0; i < 8; ++i){
      f4u qp = *(const f4u*)(shape + (size_t)(row0 + i) * 6);
      cx[i] = qp.x; cy[i] = qp.y; cz[i] = qp.z;
    }
    const float* skb = skel + (size_t)b * NS * 3;
    const float* rdb = rad + (size_t)b * NS;
    float mn[8], pm[8];
#pragma unroll
    for (int i = 0; i < 8; ++i){ mn[i] = 3.4e38f; pm[i] = 3.4e38f; }
#pragma unroll
    for (int it = 0; it < 4; ++it){
      int kidx = it * 64 + lane;
      f2u kxy = *(const f2u*)(skb + (size_t)kidx * 3);
      float kz = skb[(size_t)kidx * 3 + 2];
      float rr = rdb[kidx];
      float r2 = rr * rr;
      float c1 = M2E * rr;
#pragma unroll
      for (int i = 0; i < 8; ++i){
        float dx = cx[i] - kxy.x, dy = cy[i] - kxy.y, dz = cz[i] - kz;
        float q  = fmaf(dx, dx, fmaf(dy, dy, dz * dz));
        float s  = (fabsf(dx) + fabsf(dy)) + fabsf(dz);
        mn[i] = fminf(mn[i], fmaf(c1, s, q + r2));
        float d = sqrtf(fmaxf(q, EPS));
        pm[i] = fminf(pm[i], fabsf(d - rr));
      }
    }
    float cdv = 0.0f, pv = 0.0f;
#pragma unroll
    for (int i = 0; i < 8; ++i){
      float m = wave_min(mn[i]);
      cdv += sqrtf(fmaxf(m, EPS));
      pv  += wave_min(pm[i]);
    }
    if (lane == 0){
      ws[OFF_C2O + wv] = cdv;
      ws[OFF_P2O + wv] = pv;
    }

  } else {
    // ---- skn: single-wave role; LDS stage is same-wave (no barrier needed) ----
    int q = bid;                     // 0..2047, only <960 active
    if (q >= 960) return;
    int b = q / 120;
    int w = q % 120;
    int t = w * 64 + lane;           // 0..7679
    for (int i = lane; i < NM; i += 64){
      const float* lp = l3 + (size_t)(b * NM + i) * 3;
      float lx = lp[0], ly = lp[1], lz = lp[2];
      lsh[i] = make_float4(lx, ly, lz, fmaf(lx, lx, fmaf(ly, ly, lz * lz)));
    }
    int s = t >> 8;
    int j = t & 255;
    float ksf = (float)s * (1.0f / 30.0f);
    const float* sj = skel + (size_t)(b * NS + j) * 3;
    const float* nj = nori + (size_t)(b * NS + j) * 3;
    float px = fmaf(nj[0], ksf, sj[0]);
    float py = fmaf(nj[1], ksf, sj[1]);
    float pz = fmaf(nj[2], ksf, sj[2]);
    float ax = -2.0f * px, ay = -2.0f * py, az = -2.0f * pz;
    float pw = fmaf(px, px, fmaf(py, py, pz * pz));
    float mn = 3.4e38f;
#pragma unroll 8
    for (int qq = 0; qq < NM; ++qq){
      float4 L = lsh[qq];
      float t2 = fmaf(L.x, ax, fmaf(L.y, ay, fmaf(L.z, az, L.w)));
      mn = fminf(mn, t2);
    }
    float d = sqrtf(fmaxf(mn + pw, EPS));
    float s1 = wave_sum(d);
    float s2 = wave_sum(d * d);
    if (lane == 0){
      ws[OFF_SKS + q] = s1;
      ws[OFF_SKQ + q] = s2;
    }
  }
}

// ---- dispatch 2: finalize (1024 threads for MLP on cross-XCD reads) ----
__global__ __launch_bounds__(1024) void k_final(const float* __restrict__ rad,
                                                const float* __restrict__ ws,
                                                const int* w0, const int* w1, const int* w2,
                                                const int* w4, const int* w5, const int* w6,
                                                float* __restrict__ out){
  __shared__ float red[8][16];
  __shared__ float sb1[960], sb2[960];
  __shared__ float bb1[8], bb2[8];
  int tid = threadIdx.x;
  int wid = tid >> 6, lane = tid & 63;

  float pp2sj = 0.0f, pnorm = 0.0f, pns = 0.0f, pnd = 0.0f;
  for (int q = tid; q < 2048; q += 1024){
    float4 s4 = *(const float4*)(ws + OFF_SKO + (size_t)q * 4);
    pp2sj += s4.x; pnorm += s4.y; pns += s4.z; pnd += s4.w;
  }
  float pc1 = 0.0f;
  for (int q = tid; q < 2048; q += 1024) pc1 += ws[OFF_C1O + q];
  float pc2 = 0.0f, pp2n = 0.0f;
  for (int q = tid; q < 4096; q += 1024){
    pc2  += ws[OFF_C2O + q];
    pp2n += ws[OFF_P2O + q];
  }
  float prad = 0.0f;
  for (int q = tid; q < NB * NS; q += 1024) prad += rad[q];

  if (tid < 960){ sb1[tid] = ws[OFF_SKS + tid]; sb2[tid] = ws[OFF_SKQ + tid]; }

  pp2sj = wave_sum(pp2sj); pnorm = wave_sum(pnorm);
  pns = wave_sum(pns);     pnd = wave_sum(pnd);
  pc1 = wave_sum(pc1);     pc2 = wave_sum(pc2);
  pp2n = wave_sum(pp2n);   prad = wave_sum(prad);
  if (lane == 0){
    red[0][wid] = pp2sj; red[1][wid] = pnorm; red[2][wid] = pns; red[3][wid] = pnd;
    red[4][wid] = pc1;   red[5][wid] = pc2;   red[6][wid] = pp2n; red[7][wid] = prad;
  }
  __syncthreads();
  if (tid < 8){
    float s1 = 0.0f, s2 = 0.0f;
    for (int i = 0; i < 120; ++i){ s1 += sb1[tid * 120 + i]; s2 += sb2[tid * 120 + i]; }
    bb1[tid] = s1; bb2[tid] = s2;
  }
  __syncthreads();
  if (tid == 0){
    float acc[8];
#pragma unroll
    for (int r = 0; r < 8; ++r){
      float v = 0.0f;
#pragma unroll
      for (int i = 0; i < 16; ++i) v += red[r][i];
      acc[r] = v;
    }
    float p2sj = acc[0], nrmt = acc[1], nst = acc[2], ndt = acc[3];
    float c1t = acc[4], c2t = acc[5], p2nt = acc[6], srad = acc[7];
    float ls = c1t * (1.0f/2048.0f) + c2t * (1.0f/4096.0f);
    float lp = p2nt * (1.0f/4096.0f) + p2sj * (1.0f/256.0f);
    float lr = -srad * (1.0f/256.0f);
    float ln = nrmt * (1.0f/8.0f);
    float smind = 0.0f, vsum = 0.0f;
    for (int b = 0; b < NB; ++b){
      float s1 = bb1[b], s2 = bb2[b];
      smind += s1;
      vsum  += (s2 - s1 * s1 * (1.0f/7680.0f)) * (1.0f/7679.0f);
    }
    float lskn = 50.0f * smind * (1.0f/(8.0f*7680.0f)) + 500.0f * vsum * (1.0f/8.0f);
    float lnd = ndt * (1.0f/2048.0f);
    float lns = nst * (1.0f/6144.0f);
    float o = (float)w0[0]*ls + (float)w1[0]*lp + (float)w2[0]*lr +
              (float)w4[0]*ln + (float)w5[0]*lskn + (float)w6[0]*lnd + 0.1f*lns;
    out[0] = o;
  }
}

extern "C" void kernel_launch(void* const* d_in, const int* in_sizes, int n_in,
                              void* d_out, int out_size, void* d_ws, size_t ws_size,
                              hipStream_t stream) {
  const float* skel  = (const float*)d_in[0];
  const float* rad   = (const float*)d_in[1];
  const float* nori  = (const float*)d_in[3];
  const float* l3    = (const float*)d_in[5];
  const float* shape = (const float*)d_in[7];
  const int* w0 = (const int*)d_in[9];
  const int* w1 = (const int*)d_in[10];
  const int* w2 = (const int*)d_in[11];
  const int* w4 = (const int*)d_in[13];
  const int* w5 = (const int*)d_in[14];
  const int* w6 = (const int*)d_in[15];
  float* ws  = (float*)d_ws;
  float* out = (float*)d_out;

  k_mega<<<dim3(NBLK_MEGA), dim3(256), 0, stream>>>(skel, rad, nori, l3, shape, ws);
  k_final<<<dim3(1), dim3(1024), 0, stream>>>(rad, ws, w0, w1, w2, w4, w5, w6, out);
}